// Round 11
// baseline (1950.746 us; speedup 1.0000x reference)
//
#include <hip/hip_runtime.h>
#include <stdint.h>

#define NB 4      // batch
#define SEQ 1024  // sequence
#define DM 256    // d_model == head_dim
#define NH 8      // heads

typedef __attribute__((ext_vector_type(8))) short bf8;   // 8 bf16 (4 VGPRs)
typedef __attribute__((ext_vector_type(4))) float f4;    // MFMA accumulator

__device__ __forceinline__ unsigned short f2bf(float f) {
  union { float f; uint32_t u; } c; c.f = f;
  uint32_t u = c.u;
  return (unsigned short)((u + 0x7FFFu + ((u >> 16) & 1u)) >> 16); // RNE
}

// async global->LDS DMA, 16B per lane (m97 recipe): lds dst = base + lane*16.
__device__ __forceinline__ void gl_lds16(const unsigned short* g, short* l) {
  __builtin_amdgcn_global_load_lds(
      (const __attribute__((address_space(1))) unsigned int*)g,
      (__attribute__((address_space(3))) unsigned int*)l, 16, 0, 0);
}

// Fragment-major layouts (per bh slice = 262144 elems = 512 KB):
//  q_frag/k_frag: [tile16 (token/16)][dchunk (d/32)][lane64][j8]
//     element (tok = tile*16 + (lane&15), d = dchunk*32 + (lane>>4)*8 + j)
//  v_frag:        [dtile (d/16)][kvchunk (kv/32)][lane64][j8]
//     element (d = dtile*16 + (lane&15), kv = kvchunk*32 + (lane>>4)*8 + j)

// ---------------------------------------------------------------------------
// Kernel 0: ALL prep in one launch.  grid (1024, 7), 256 thr.
// ---------------------------------------------------------------------------
__global__ __launch_bounds__(256) void prep_kernel(
    const float* __restrict__ Wq, const float* __restrict__ Wk,
    const float* __restrict__ Wv, const float* __restrict__ Wo,
    const float* __restrict__ Q, const float* __restrict__ K,
    const float* __restrict__ V,
    unsigned short* __restrict__ Wt3, unsigned short* __restrict__ WoT,
    unsigned short* __restrict__ Xbf) {
  const int z = blockIdx.y;
  const int tid = threadIdx.x;
  if (z >= 4) {
    const float* src = (z == 4) ? Q : (z == 5) ? K : V;
    const size_t off = (size_t)blockIdx.x * 1024 + tid * 4;
    const float4 v = *(const float4*)(src + off);
    short4 s;
    s.x = (short)f2bf(v.x); s.y = (short)f2bf(v.y);
    s.z = (short)f2bf(v.z); s.w = (short)f2bf(v.w);
    *(short4*)(Xbf + (size_t)(z - 4) * 4096 * 256 + off) = s;
    return;
  }
  if (blockIdx.x >= 512) return;
  const float* in;
  unsigned short* out;
  int R, C, bx, by;
  if (z < 3) {
    in = (z == 0) ? Wq : (z == 1) ? Wk : Wv;
    out = Wt3 + (size_t)z * 2048 * 256;
    R = 256; C = 2048; bx = blockIdx.x & 63; by = blockIdx.x >> 6;
  } else {
    in = Wo; out = WoT;
    R = 2048; C = 256; bx = blockIdx.x & 7; by = blockIdx.x >> 3;
  }
  __shared__ float t[32][33];
  const int c0 = bx * 32, r0 = by * 32;
  const int tx = tid & 31, ty = tid >> 5;
#pragma unroll
  for (int i = 0; i < 4; i++) {
    int r = r0 + ty + i * 8;
    t[ty + i * 8][tx] = in[(size_t)r * C + c0 + tx];
  }
  __syncthreads();
#pragma unroll
  for (int i = 0; i < 4; i++) {
    int c = c0 + ty + i * 8;
    out[(size_t)c * R + r0 + tx] = f2bf(t[tx][ty + i * 8]);
  }
}

// ---------------------------------------------------------------------------
// Kernel 1: QKV projection GEMM, m97-style body.
// z<2 (q,k): MFMA computes Y^T (A=W-frag, B=X-frag) so the C-layout reg dim
// lands on d -> short4 stores, one contiguous 512B segment per wave-store
// (was 64 scattered b16 stores = 8 segments each).  Layout bit-identical.
// z=2 (v): original orientation (reg dim = token = kv) with short4 stores.
// ---------------------------------------------------------------------------
__global__ __launch_bounds__(256) void proj_kernel(
    const unsigned short* __restrict__ Xbf, const unsigned short* __restrict__ Wt3,
    const float* __restrict__ bq, const float* __restrict__ bk, const float* __restrict__ bv,
    unsigned short* __restrict__ q_frag, unsigned short* __restrict__ k_frag,
    unsigned short* __restrict__ v_frag) {
  const int z = blockIdx.z;
  const unsigned short* X = Xbf + (size_t)z * 4096 * 256;
  const unsigned short* Wt = Wt3 + (size_t)z * 2048 * 256;
  const float* bias = (z == 0) ? bq : (z == 1) ? bk : bv;

  __shared__ short a_lds[128 * 32];
  __shared__ short b_lds[128 * 32];

  const int tid = threadIdx.x;
  const int wid = tid >> 6, lane = tid & 63;
  const int quad = lane >> 4, l16 = lane & 15;
  const int wm = wid >> 1, wn = wid & 1;
  const int m0 = blockIdx.x * 128, n0 = blockIdx.y * 128;

  f4 acc[4][4];
  const f4 z4 = {0.f, 0.f, 0.f, 0.f};
#pragma unroll
  for (int i = 0; i < 4; i++)
#pragma unroll
    for (int j = 0; j < 4; j++) acc[i][j] = z4;

  const int srow = lane >> 2;
  const int schunk = lane & 3;
  const int cxor = quad ^ (l16 & 3);

  for (int ko = 0; ko < 8; ko++) {
    const int k0 = ko * 32;
#pragma unroll
    for (int j = 0; j < 2; j++) {
      const int i = wid * 2 + j;
      const int row = i * 16 + srow;
      const int sc = (schunk ^ (row & 3)) * 8;
      gl_lds16(X + (size_t)(m0 + row) * DM + k0 + sc, a_lds + i * 512);
      gl_lds16(Wt + (size_t)(n0 + row) * DM + k0 + sc, b_lds + i * 512);
    }
    __syncthreads();
    bf8 af[4], bfv[4];
#pragma unroll
    for (int mi = 0; mi < 4; mi++)
      af[mi] = *(const bf8*)(a_lds + (wm * 64 + mi * 16 + l16) * 32 + cxor * 8);
#pragma unroll
    for (int ni = 0; ni < 4; ni++)
      bfv[ni] = *(const bf8*)(b_lds + (wn * 64 + ni * 16 + l16) * 32 + cxor * 8);
    if (z < 2) {
#pragma unroll
      for (int ni = 0; ni < 4; ni++)
#pragma unroll
        for (int mi = 0; mi < 4; mi++)
          acc[ni][mi] = __builtin_amdgcn_mfma_f32_16x16x32_bf16(bfv[ni], af[mi], acc[ni][mi], 0, 0, 0);
    } else {
#pragma unroll
      for (int mi = 0; mi < 4; mi++)
#pragma unroll
        for (int ni = 0; ni < 4; ni++)
          acc[mi][ni] = __builtin_amdgcn_mfma_f32_16x16x32_bf16(af[mi], bfv[ni], acc[mi][ni], 0, 0, 0);
    }
    __syncthreads();
  }

  if (z < 2) {
    // Y^T: acc[ni][mi] row = d (quad*4+reg), col = token (l16)
    // q scale folds 1/sqrt(256) AND log2(e) (softmax uses exp2 directly)
    const float scale = (z == 0) ? 0.0901684400f : 1.0f;
    unsigned short* dst = (z == 0) ? q_frag : k_frag;
#pragma unroll
    for (int ni = 0; ni < 4; ni++) {
      const int nb = n0 + wn * 64 + ni * 16 + quad * 4;  // 4 consecutive n(=d)
      const float4 b4 = *(const float4*)(bias + nb);
      const int h = nb >> 8, dd = nb & 255;
      const int dq = (dd >> 3) & 3, jh = dd & 7;         // jh in {0,4}
#pragma unroll
      for (int mi = 0; mi < 4; mi++) {
        const int tok = m0 + wm * 64 + mi * 16 + l16;
        const int b = tok >> 10, sr = tok & 1023;
        const size_t idx = ((size_t)(b * NH + h) * 64 + (sr >> 4)) * 4096 +
                           (size_t)(dd >> 5) * 512 + ((sr & 15) + 16 * dq) * 8 + jh;
        short4 s4;
        s4.x = (short)f2bf((acc[ni][mi][0] + b4.x) * scale);
        s4.y = (short)f2bf((acc[ni][mi][1] + b4.y) * scale);
        s4.z = (short)f2bf((acc[ni][mi][2] + b4.z) * scale);
        s4.w = (short)f2bf((acc[ni][mi][3] + b4.w) * scale);
        *(short4*)(dst + idx) = s4;
      }
    }
  } else {
#pragma unroll
    for (int ni = 0; ni < 4; ni++) {
      const int n = n0 + wn * 64 + ni * 16 + l16;
      const float bsv = bias[n];
      const int h = n >> 8, d = n & 255;
#pragma unroll
      for (int mi = 0; mi < 4; mi++) {
        const int m = m0 + wm * 64 + mi * 16 + quad * 4;
        const int b = m >> 10, sr = m & 1023;
        const size_t idx = ((size_t)(b * NH + h) * 16 + (d >> 4)) * 16384 +
                           (size_t)(sr >> 5) * 512 +
                           ((d & 15) + 16 * ((sr >> 3) & 3)) * 8 + (sr & 7);
        short4 s4;
        s4.x = (short)f2bf(acc[mi][ni][0] + bsv);
        s4.y = (short)f2bf(acc[mi][ni][1] + bsv);
        s4.z = (short)f2bf(acc[mi][ni][2] + bsv);
        s4.w = (short)f2bf(acc[mi][ni][3] + bsv);
        *(short4*)(v_frag + idx) = s4;
      }
    }
  }
}

// ---------------------------------------------------------------------------
// Kernel 2: flash attention v11 — single-barrier software pipeline.
// Every __syncthreads drains vmcnt(0) (structural), so R10's 2-barrier loop
// exposed V latency + K-DMA drain each t.  v11: double-buffered k_lds AND
// p_lds, PV shifted one iteration behind S.  Per iter t (kv tile = 32):
//   V(t)->regs | S(t) from k_lds[t&1] | DMA K(t+1)->k_lds[~t] |
//   PV(t-1) from vpre[~t]+p_lds[~t] | softmax(t)->p_lds[t&1] | ONE barrier
// All loads get ~a full iteration before their drain point.
// exp2 direct (log2e folded into q scale); P round-half-up (2 ops).
// LDS 43.3 KB, grid 512, XCD swizzle kept.
// ---------------------------------------------------------------------------
__global__ __launch_bounds__(256) void attn_kernel(
    const unsigned short* __restrict__ q_frag, const unsigned short* __restrict__ k_frag,
    const unsigned short* __restrict__ v_frag, unsigned short* __restrict__ o_ws) {
  __shared__ short k_lds[2][8192];    // 2 x (32 kv x 256 d) fragment-major
  __shared__ short p_lds[2][64][40];  // 2 x (64 q x 32 kv), stride 80B (16B-aligned)
  __shared__ float l_sh[64];

  const int tid = threadIdx.x;
  const int wid = tid >> 6, lane = tid & 63;
  const int quad = lane >> 4, l16 = lane & 15;
  const int blk = blockIdx.x;
  const int g = blk & 7;                 // XCD (dispatch round-robin heuristic)
  const int qt = (blk >> 3) & 15;        // q tile (64 rows)
  const int bh = g + 8 * (blk >> 7);     // 16 same-bh blocks share one XCD
  const size_t fbase = (size_t)bh * 262144;

  // Q fragments: wave's own 16 q-rows, all 8 d-chunks (coalesced, once).
  bf8 qf[8];
  {
    const unsigned short* qp = q_frag + fbase + (size_t)(qt * 4 + wid) * 4096 + lane * 8;
#pragma unroll
    for (int kc = 0; kc < 8; kc++) qf[kc] = *(const bf8*)(qp + kc * 512);
  }

  const f4 z4 = {0.f, 0.f, 0.f, 0.f};
  f4 Oacc[4][4];  // [mi(d)][nq(q)]: d = wid*64+mi*16+quad*4+reg, q = nq*16+l16
#pragma unroll
  for (int i = 0; i < 4; i++)
#pragma unroll
    for (int j = 0; j < 4; j++) Oacc[i][j] = z4;
  float lpart[4] = {0.f, 0.f, 0.f, 0.f};

  // K DMA: tile t = 16 KB at sh offset t*8192; wave wid copies sh [wid*2048,+2048)
  const unsigned short* kdma_src = k_frag + fbase + (size_t)wid * 2048 + lane * 8;
  // prologue: DMA K(0) into buffer 0
#pragma unroll
  for (int jj = 0; jj < 4; jj++)
    gl_lds16(kdma_src + jj * 512, &k_lds[0][wid * 2048 + jj * 512]);
  __syncthreads();

  bf8 vpre[2][4];
  const unsigned short* vbase_p = v_frag + fbase + (size_t)(wid * 4) * 16384 + lane * 8;

  for (int t = 0; t < 32; t++) {
    const int cur = t & 1, prv = cur ^ 1;
    // ---- V(t) prefetch (consumed by PV(t) in iteration t+1)
#pragma unroll
    for (int mi = 0; mi < 4; mi++)
      vpre[cur][mi] = *(const bf8*)(vbase_p + (size_t)mi * 16384 + (size_t)t * 512);
    // ---- S(t): [16q_own x 32kv], K=256.  A=qf, B from k_lds[cur].
    f4 Sacc[2];
    Sacc[0] = z4; Sacc[1] = z4;
#pragma unroll
    for (int kc = 0; kc < 8; kc++) {
      const bf8 aq = qf[kc];
#pragma unroll
      for (int ni = 0; ni < 2; ni++) {
        const bf8 kb = *(const bf8*)(&k_lds[cur][(ni * 8 + kc) * 512 + lane * 8]);
        Sacc[ni] = __builtin_amdgcn_mfma_f32_16x16x32_bf16(aq, kb, Sacc[ni], 0, 0, 0);
      }
    }
    // ---- DMA K(t+1) into the other buffer (drains at this iter's barrier)
    if (t < 31) {
#pragma unroll
      for (int jj = 0; jj < 4; jj++)
        gl_lds16(kdma_src + (size_t)(t + 1) * 8192 + jj * 512,
                 &k_lds[prv][wid * 2048 + jj * 512]);
    }
    // ---- PV(t-1): O^T[64d_own x 64q] += V^T P^T from vpre[prv] + p_lds[prv]
    if (t > 0) {
      bf8 pb[4];
#pragma unroll
      for (int nq = 0; nq < 4; nq++)
        pb[nq] = *(const bf8*)(&p_lds[prv][nq * 16 + l16][quad * 8]);
#pragma unroll
      for (int mi = 0; mi < 4; mi++)
#pragma unroll
        for (int nq = 0; nq < 4; nq++)
          Oacc[mi][nq] = __builtin_amdgcn_mfma_f32_16x16x32_bf16(vpre[prv][mi], pb[nq], Oacc[mi][nq], 0, 0, 0);
    }
    // ---- softmax(t): exp2 (log2e pre-folded), l partials, P -> p_lds[cur]
#pragma unroll
    for (int reg = 0; reg < 4; reg++) {
      const int qrow = wid * 16 + quad * 4 + reg;
      float s = 0.f;
#pragma unroll
      for (int ni = 0; ni < 2; ni++) {
        const float p = exp2f(Sacc[ni][reg]);
        s += p;
        union { float f; uint32_t u; } c; c.f = p;
        p_lds[cur][qrow][ni * 16 + l16] = (short)((c.u + 0x8000u) >> 16);
      }
      lpart[reg] += s;
    }
    __syncthreads();  // the ONE barrier: publishes p(t), drains K(t+1) DMA
  }
  // ---- drain: PV(31) from buffers of t=31 (cur of last iter = 1)
  {
    bf8 pb[4];
#pragma unroll
    for (int nq = 0; nq < 4; nq++)
      pb[nq] = *(const bf8*)(&p_lds[1][nq * 16 + l16][quad * 8]);
#pragma unroll
    for (int mi = 0; mi < 4; mi++)
#pragma unroll
      for (int nq = 0; nq < 4; nq++)
        Oacc[mi][nq] = __builtin_amdgcn_mfma_f32_16x16x32_bf16(vpre[1][mi], pb[nq], Oacc[mi][nq], 0, 0, 0);
  }

  // ---- final l: reduce over 16 kv-col lanes (each q owned by one wave)
#pragma unroll
  for (int reg = 0; reg < 4; reg++) {
    float v = lpart[reg];
    v += __shfl_xor(v, 1, 64);
    v += __shfl_xor(v, 2, 64);
    v += __shfl_xor(v, 4, 64);
    v += __shfl_xor(v, 8, 64);
    if (l16 == 0) l_sh[wid * 16 + quad * 4 + reg] = v;
  }
  __syncthreads();

  // ---- epilogue: O^T[d][q] / l(q) -> o_ws [B,S,H*256]
  const int b = bh >> 3, h = bh & 7;
#pragma unroll
  for (int nq = 0; nq < 4; nq++) {
    const int q = nq * 16 + l16;
    const float inv = 1.f / l_sh[q];
    const size_t base = ((size_t)b * SEQ + qt * 64 + q) * (NH * DM) + h * DM + wid * 64;
#pragma unroll
    for (int mi = 0; mi < 4; mi++) {
      short4 s4;
      s4.x = (short)f2bf(Oacc[mi][nq][0] * inv);
      s4.y = (short)f2bf(Oacc[mi][nq][1] * inv);
      s4.z = (short)f2bf(Oacc[mi][nq][2] * inv);
      s4.w = (short)f2bf(Oacc[mi][nq][3] * inv);
      *(short4*)(o_ws + base + mi * 16 + quad * 4) = s4;
    }
  }
}

// ---------------------------------------------------------------------------
// Kernel 3: output projection.  BM=32, BN=64, BK=128, grid (128,4).
// ---------------------------------------------------------------------------
__global__ __launch_bounds__(256) void outproj_kernel(
    const unsigned short* __restrict__ o_ws, const unsigned short* __restrict__ WoT,
    const float* __restrict__ bo, float* __restrict__ out) {
  __shared__ short a_lds[32][136];
  __shared__ short b_lds[64][136];

  const int tid = threadIdx.x;
  const int wid = tid >> 6, lane = tid & 63;
  const int quad = lane >> 4, l16 = lane & 15;
  const int wm = wid & 1, wn = wid >> 1;
  const int m0 = blockIdx.x * 32, n0 = blockIdx.y * 64;

  const f4 z4 = {0.f, 0.f, 0.f, 0.f};
  f4 acc[2];
#pragma unroll
  for (int i = 0; i < 2; i++) acc[i] = z4;

  const int ch = tid & 15, row = tid >> 4;
  for (int ko = 0; ko < 16; ko++) {
    const int k0 = ko * 128;
#pragma unroll
    for (int rb = 0; rb < 2; rb++) {
      int r = row + rb * 16;
      *(bf8*)(&a_lds[r][ch * 8]) = *(const bf8*)(o_ws + (size_t)(m0 + r) * 2048 + k0 + ch * 8);
    }
#pragma unroll
    for (int rb = 0; rb < 4; rb++) {
      int r = row + rb * 16;
      *(bf8*)(&b_lds[r][ch * 8]) = *(const bf8*)(WoT + (size_t)(n0 + r) * 2048 + k0 + ch * 8);
    }
    __syncthreads();
#pragma unroll
    for (int kc = 0; kc < 4; kc++) {
      const bf8 af = *(const bf8*)(&a_lds[wm * 16 + l16][kc * 32 + quad * 8]);
      bf8 bfv[2];
#pragma unroll
      for (int ni = 0; ni < 2; ni++)
        bfv[ni] = *(const bf8*)(&b_lds[wn * 32 + ni * 16 + l16][kc * 32 + quad * 8]);
#pragma unroll
      for (int ni = 0; ni < 2; ni++)
        acc[ni] = __builtin_amdgcn_mfma_f32_16x16x32_bf16(af, bfv[ni], acc[ni], 0, 0, 0);
    }
    __syncthreads();
  }
#pragma unroll
  for (int ni = 0; ni < 2; ni++) {
    const int n = n0 + wn * 32 + ni * 16 + l16;
    const float bv = bo[n];
#pragma unroll
    for (int reg = 0; reg < 4; reg++) {
      const int m = m0 + wm * 16 + quad * 4 + reg;
      out[(size_t)m * DM + n] = acc[ni][reg] + bv;
    }
  }
}

// ---------------------------------------------------------------------------
extern "C" void kernel_launch(void* const* d_in, const int* in_sizes, int n_in,
                              void* d_out, int out_size, void* d_ws, size_t ws_size,
                              hipStream_t stream) {
  const float* Q  = (const float*)d_in[0];
  const float* K  = (const float*)d_in[1];
  const float* V  = (const float*)d_in[2];
  const float* Wq = (const float*)d_in[3];
  const float* bq = (const float*)d_in[4];
  const float* Wk = (const float*)d_in[5];
  const float* bk = (const float*)d_in[6];
  const float* Wv = (const float*)d_in[7];
  const float* bv = (const float*)d_in[8];
  const float* Wo = (const float*)d_in[9];
  const float* bo = (const float*)d_in[10];
  float* out = (float*)d_out;

  char* ws = (char*)d_ws;
  const size_t QS = (size_t)NB * NH * SEQ * DM * 2;  // 16 MiB each
  unsigned short* q_frag = (unsigned short*)(ws);
  unsigned short* k_frag = (unsigned short*)(ws + QS);
  unsigned short* v_frag = (unsigned short*)(ws + 2 * QS);
  unsigned short* o_ws   = (unsigned short*)(ws + 3 * QS);
  const size_t WT = (size_t)2048 * 256 * 2;  // 1 MiB each
  unsigned short* Wt3 = (unsigned short*)(ws + 4 * QS);           // 3 MiB
  unsigned short* WoT = (unsigned short*)(ws + 4 * QS + 3 * WT);  // 1 MiB
  // Xbf (6 MiB) aliases o_ws: proj reads it before attn overwrites o_ws.
  unsigned short* Xbf = o_ws;

  prep_kernel<<<dim3(1024, 7), 256, 0, stream>>>(Wq, Wk, Wv, Wo, Q, K, V,
                                                 Wt3, WoT, Xbf);
  proj_kernel<<<dim3(32, 16, 3), 256, 0, stream>>>(Xbf, Wt3, bq, bk, bv,
                                                   q_frag, k_frag, v_frag);
  attn_kernel<<<512, 256, 0, stream>>>(q_frag, k_frag, v_frag, o_ws);
  outproj_kernel<<<dim3(128, 4), 256, 0, stream>>>(o_ws, WoT, bo, out);
}

// Round 12
// 169.638 us; speedup vs baseline: 11.4995x; 11.4995x over previous
//
#include <hip/hip_runtime.h>
#include <stdint.h>

#define NB 4      // batch
#define SEQ 1024  // sequence
#define DM 256    // d_model == head_dim
#define NH 8      // heads

typedef __attribute__((ext_vector_type(8))) short bf8;   // 8 bf16 (4 VGPRs)
typedef __attribute__((ext_vector_type(4))) float f4;    // MFMA accumulator

__device__ __forceinline__ unsigned short f2bf(float f) {
  union { float f; uint32_t u; } c; c.f = f;
  uint32_t u = c.u;
  return (unsigned short)((u + 0x7FFFu + ((u >> 16) & 1u)) >> 16); // RNE
}

// async global->LDS DMA, 16B per lane (m97 recipe): lds dst = base + lane*16.
__device__ __forceinline__ void gl_lds16(const unsigned short* g, short* l) {
  __builtin_amdgcn_global_load_lds(
      (const __attribute__((address_space(1))) unsigned int*)g,
      (__attribute__((address_space(3))) unsigned int*)l, 16, 0, 0);
}

// Fragment-major layouts (per bh slice = 262144 elems = 512 KB):
//  q_frag/k_frag: [tile16 (token/16)][dchunk (d/32)][lane64][j8]
//  v_frag:        [dtile (d/16)][kvchunk (kv/32)][lane64][j8]

// ---------------------------------------------------------------------------
// Kernel 0: ALL prep in one launch.  grid (1024, 7), 256 thr.
// ---------------------------------------------------------------------------
__global__ __launch_bounds__(256) void prep_kernel(
    const float* __restrict__ Wq, const float* __restrict__ Wk,
    const float* __restrict__ Wv, const float* __restrict__ Wo,
    const float* __restrict__ Q, const float* __restrict__ K,
    const float* __restrict__ V,
    unsigned short* __restrict__ Wt3, unsigned short* __restrict__ WoT,
    unsigned short* __restrict__ Xbf) {
  const int z = blockIdx.y;
  const int tid = threadIdx.x;
  if (z >= 4) {
    const float* src = (z == 4) ? Q : (z == 5) ? K : V;
    const size_t off = (size_t)blockIdx.x * 1024 + tid * 4;
    const float4 v = *(const float4*)(src + off);
    short4 s;
    s.x = (short)f2bf(v.x); s.y = (short)f2bf(v.y);
    s.z = (short)f2bf(v.z); s.w = (short)f2bf(v.w);
    *(short4*)(Xbf + (size_t)(z - 4) * 4096 * 256 + off) = s;
    return;
  }
  if (blockIdx.x >= 512) return;
  const float* in;
  unsigned short* out;
  int R, C, bx, by;
  if (z < 3) {
    in = (z == 0) ? Wq : (z == 1) ? Wk : Wv;
    out = Wt3 + (size_t)z * 2048 * 256;
    R = 256; C = 2048; bx = blockIdx.x & 63; by = blockIdx.x >> 6;
  } else {
    in = Wo; out = WoT;
    R = 2048; C = 256; bx = blockIdx.x & 7; by = blockIdx.x >> 3;
  }
  __shared__ float t[32][33];
  const int c0 = bx * 32, r0 = by * 32;
  const int tx = tid & 31, ty = tid >> 5;
#pragma unroll
  for (int i = 0; i < 4; i++) {
    int r = r0 + ty + i * 8;
    t[ty + i * 8][tx] = in[(size_t)r * C + c0 + tx];
  }
  __syncthreads();
#pragma unroll
  for (int i = 0; i < 4; i++) {
    int c = c0 + ty + i * 8;
    out[(size_t)c * R + r0 + tx] = f2bf(t[tx][ty + i * 8]);
  }
}

// ---------------------------------------------------------------------------
// Kernel 1: QKV projection GEMM, m97-style body; Y^T epilogue for q/k
// (contiguous 512B wave-stores), short4 everywhere.  (unchanged from R11)
// ---------------------------------------------------------------------------
__global__ __launch_bounds__(256) void proj_kernel(
    const unsigned short* __restrict__ Xbf, const unsigned short* __restrict__ Wt3,
    const float* __restrict__ bq, const float* __restrict__ bk, const float* __restrict__ bv,
    unsigned short* __restrict__ q_frag, unsigned short* __restrict__ k_frag,
    unsigned short* __restrict__ v_frag) {
  const int z = blockIdx.z;
  const unsigned short* X = Xbf + (size_t)z * 4096 * 256;
  const unsigned short* Wt = Wt3 + (size_t)z * 2048 * 256;
  const float* bias = (z == 0) ? bq : (z == 1) ? bk : bv;

  __shared__ short a_lds[128 * 32];
  __shared__ short b_lds[128 * 32];

  const int tid = threadIdx.x;
  const int wid = tid >> 6, lane = tid & 63;
  const int quad = lane >> 4, l16 = lane & 15;
  const int wm = wid >> 1, wn = wid & 1;
  const int m0 = blockIdx.x * 128, n0 = blockIdx.y * 128;

  f4 acc[4][4];
  const f4 z4 = {0.f, 0.f, 0.f, 0.f};
#pragma unroll
  for (int i = 0; i < 4; i++)
#pragma unroll
    for (int j = 0; j < 4; j++) acc[i][j] = z4;

  const int srow = lane >> 2;
  const int schunk = lane & 3;
  const int cxor = quad ^ (l16 & 3);

  for (int ko = 0; ko < 8; ko++) {
    const int k0 = ko * 32;
#pragma unroll
    for (int j = 0; j < 2; j++) {
      const int i = wid * 2 + j;
      const int row = i * 16 + srow;
      const int sc = (schunk ^ (row & 3)) * 8;
      gl_lds16(X + (size_t)(m0 + row) * DM + k0 + sc, a_lds + i * 512);
      gl_lds16(Wt + (size_t)(n0 + row) * DM + k0 + sc, b_lds + i * 512);
    }
    __syncthreads();
    bf8 af[4], bfv[4];
#pragma unroll
    for (int mi = 0; mi < 4; mi++)
      af[mi] = *(const bf8*)(a_lds + (wm * 64 + mi * 16 + l16) * 32 + cxor * 8);
#pragma unroll
    for (int ni = 0; ni < 4; ni++)
      bfv[ni] = *(const bf8*)(b_lds + (wn * 64 + ni * 16 + l16) * 32 + cxor * 8);
    if (z < 2) {
#pragma unroll
      for (int ni = 0; ni < 4; ni++)
#pragma unroll
        for (int mi = 0; mi < 4; mi++)
          acc[ni][mi] = __builtin_amdgcn_mfma_f32_16x16x32_bf16(bfv[ni], af[mi], acc[ni][mi], 0, 0, 0);
    } else {
#pragma unroll
      for (int mi = 0; mi < 4; mi++)
#pragma unroll
        for (int ni = 0; ni < 4; ni++)
          acc[mi][ni] = __builtin_amdgcn_mfma_f32_16x16x32_bf16(af[mi], bfv[ni], acc[mi][ni], 0, 0, 0);
    }
    __syncthreads();
  }

  if (z < 2) {
    // q scale folds 1/sqrt(256) AND log2(e) (softmax uses exp2 directly)
    const float scale = (z == 0) ? 0.0901684400f : 1.0f;
    unsigned short* dst = (z == 0) ? q_frag : k_frag;
#pragma unroll
    for (int ni = 0; ni < 4; ni++) {
      const int nb = n0 + wn * 64 + ni * 16 + quad * 4;  // 4 consecutive d
      const float4 b4 = *(const float4*)(bias + nb);
      const int h = nb >> 8, dd = nb & 255;
      const int dq = (dd >> 3) & 3, jh = dd & 7;
#pragma unroll
      for (int mi = 0; mi < 4; mi++) {
        const int tok = m0 + wm * 64 + mi * 16 + l16;
        const int b = tok >> 10, sr = tok & 1023;
        const size_t idx = ((size_t)(b * NH + h) * 64 + (sr >> 4)) * 4096 +
                           (size_t)(dd >> 5) * 512 + ((sr & 15) + 16 * dq) * 8 + jh;
        short4 s4;
        s4.x = (short)f2bf((acc[ni][mi][0] + b4.x) * scale);
        s4.y = (short)f2bf((acc[ni][mi][1] + b4.y) * scale);
        s4.z = (short)f2bf((acc[ni][mi][2] + b4.z) * scale);
        s4.w = (short)f2bf((acc[ni][mi][3] + b4.w) * scale);
        *(short4*)(dst + idx) = s4;
      }
    }
  } else {
#pragma unroll
    for (int ni = 0; ni < 4; ni++) {
      const int n = n0 + wn * 64 + ni * 16 + l16;
      const float bsv = bias[n];
      const int h = n >> 8, d = n & 255;
#pragma unroll
      for (int mi = 0; mi < 4; mi++) {
        const int m = m0 + wm * 64 + mi * 16 + quad * 4;
        const int b = m >> 10, sr = m & 1023;
        const size_t idx = ((size_t)(b * NH + h) * 16 + (d >> 4)) * 16384 +
                           (size_t)(sr >> 5) * 512 +
                           ((d & 15) + 16 * ((sr >> 3) & 3)) * 8 + (sr & 7);
        short4 s4;
        s4.x = (short)f2bf(acc[mi][ni][0] + bsv);
        s4.y = (short)f2bf(acc[mi][ni][1] + bsv);
        s4.z = (short)f2bf(acc[mi][ni][2] + bsv);
        s4.w = (short)f2bf(acc[mi][ni][3] + bsv);
        *(short4*)(v_frag + idx) = s4;
      }
    }
  }
}

// ---------------------------------------------------------------------------
// Kernel 2: flash attention v12 = v11 pipeline with COMPILE-TIME buffer
// indices.  R11's 31x regression: vpre[2][4] indexed by runtime t&1 ->
// register array demoted to select-chains/scratch (VGPR 140, VALU x25).
// Fix: unroll-by-2 macro; CUR/PRV are literals, vpre0/vpre1 plain arrays.
// Per step t: V(t)->vpreCUR | S(t) from k_lds[CUR] | DMA K(t+1)->k_lds[PRV]
//   | PV(t-1) from vprePRV+p_lds[PRV] | softmax(t)->p_lds[CUR] | 1 barrier.
// LDS 43.3 KB, grid 512, XCD swizzle.
// ---------------------------------------------------------------------------
__global__ __launch_bounds__(256) void attn_kernel(
    const unsigned short* __restrict__ q_frag, const unsigned short* __restrict__ k_frag,
    const unsigned short* __restrict__ v_frag, unsigned short* __restrict__ o_ws) {
  __shared__ short k_lds[2][8192];    // 2 x (32 kv x 256 d) fragment-major
  __shared__ short p_lds[2][64][40];  // 2 x (64 q x 32 kv)
  __shared__ float l_sh[64];

  const int tid = threadIdx.x;
  const int wid = tid >> 6, lane = tid & 63;
  const int quad = lane >> 4, l16 = lane & 15;
  const int blk = blockIdx.x;
  const int g = blk & 7;                 // XCD (dispatch round-robin heuristic)
  const int qt = (blk >> 3) & 15;        // q tile (64 rows)
  const int bh = g + 8 * (blk >> 7);     // 16 same-bh blocks share one XCD
  const size_t fbase = (size_t)bh * 262144;

  // Q fragments: wave's own 16 q-rows, all 8 d-chunks (coalesced, once).
  bf8 qf[8];
  {
    const unsigned short* qp = q_frag + fbase + (size_t)(qt * 4 + wid) * 4096 + lane * 8;
#pragma unroll
    for (int kc = 0; kc < 8; kc++) qf[kc] = *(const bf8*)(qp + kc * 512);
  }

  const f4 z4 = {0.f, 0.f, 0.f, 0.f};
  f4 Oacc[4][4];  // [mi(d)][nq(q)]: d = wid*64+mi*16+quad*4+reg, q = nq*16+l16
#pragma unroll
  for (int i = 0; i < 4; i++)
#pragma unroll
    for (int j = 0; j < 4; j++) Oacc[i][j] = z4;
  float lpart[4] = {0.f, 0.f, 0.f, 0.f};

  const unsigned short* kdma_src = k_frag + fbase + (size_t)wid * 2048 + lane * 8;
  // prologue: DMA K(0) into buffer 0
#pragma unroll
  for (int jj = 0; jj < 4; jj++)
    gl_lds16(kdma_src + jj * 512, &k_lds[0][wid * 2048 + jj * 512]);
  __syncthreads();

  bf8 vpre0[4], vpre1[4];
  const unsigned short* vbase_p = v_frag + fbase + (size_t)(wid * 4) * 16384 + lane * 8;

#define ATTN_STEP(T, CUR, PRV, VCUR, VPRV)                                     \
  {                                                                            \
    const int t_ = (T);                                                        \
    _Pragma("unroll")                                                          \
    for (int mi = 0; mi < 4; mi++)                                             \
      VCUR[mi] = *(const bf8*)(vbase_p + (size_t)mi * 16384 + (size_t)t_ * 512); \
    f4 Sacc[2];                                                                \
    Sacc[0] = z4; Sacc[1] = z4;                                                \
    _Pragma("unroll")                                                          \
    for (int kc = 0; kc < 8; kc++) {                                           \
      const bf8 aq = qf[kc];                                                   \
      _Pragma("unroll")                                                        \
      for (int ni = 0; ni < 2; ni++) {                                         \
        const bf8 kb = *(const bf8*)(&k_lds[CUR][(ni * 8 + kc) * 512 + lane * 8]); \
        Sacc[ni] = __builtin_amdgcn_mfma_f32_16x16x32_bf16(aq, kb, Sacc[ni], 0, 0, 0); \
      }                                                                        \
    }                                                                          \
    if (t_ < 31) {                                                             \
      _Pragma("unroll")                                                        \
      for (int jj = 0; jj < 4; jj++)                                           \
        gl_lds16(kdma_src + (size_t)(t_ + 1) * 8192 + jj * 512,                \
                 &k_lds[PRV][wid * 2048 + jj * 512]);                          \
    }                                                                          \
    if (t_ > 0) {                                                              \
      bf8 pb[4];                                                               \
      _Pragma("unroll")                                                        \
      for (int nq = 0; nq < 4; nq++)                                           \
        pb[nq] = *(const bf8*)(&p_lds[PRV][nq * 16 + l16][quad * 8]);          \
      _Pragma("unroll")                                                        \
      for (int mi = 0; mi < 4; mi++)                                           \
        _Pragma("unroll")                                                      \
        for (int nq = 0; nq < 4; nq++)                                         \
          Oacc[mi][nq] = __builtin_amdgcn_mfma_f32_16x16x32_bf16(VPRV[mi], pb[nq], Oacc[mi][nq], 0, 0, 0); \
    }                                                                          \
    _Pragma("unroll")                                                          \
    for (int reg = 0; reg < 4; reg++) {                                        \
      const int qrow = wid * 16 + quad * 4 + reg;                              \
      float s = 0.f;                                                           \
      _Pragma("unroll")                                                        \
      for (int ni = 0; ni < 2; ni++) {                                         \
        const float p = exp2f(Sacc[ni][reg]);                                  \
        s += p;                                                                \
        union { float f; uint32_t u; } c;                                      \
        c.f = p;                                                               \
        p_lds[CUR][qrow][ni * 16 + l16] = (short)((c.u + 0x8000u) >> 16);      \
      }                                                                        \
      lpart[reg] += s;                                                         \
    }                                                                          \
    __syncthreads();                                                           \
  }

  for (int tt = 0; tt < 16; tt++) {
    ATTN_STEP(tt * 2, 0, 1, vpre0, vpre1)
    ATTN_STEP(tt * 2 + 1, 1, 0, vpre1, vpre0)
  }
#undef ATTN_STEP

  // ---- drain: PV(31) from buffers of t=31 (CUR was 1)
  {
    bf8 pb[4];
#pragma unroll
    for (int nq = 0; nq < 4; nq++)
      pb[nq] = *(const bf8*)(&p_lds[1][nq * 16 + l16][quad * 8]);
#pragma unroll
    for (int mi = 0; mi < 4; mi++)
#pragma unroll
      for (int nq = 0; nq < 4; nq++)
        Oacc[mi][nq] = __builtin_amdgcn_mfma_f32_16x16x32_bf16(vpre1[mi], pb[nq], Oacc[mi][nq], 0, 0, 0);
  }

  // ---- final l: reduce over 16 kv-col lanes (each q owned by one wave)
#pragma unroll
  for (int reg = 0; reg < 4; reg++) {
    float v = lpart[reg];
    v += __shfl_xor(v, 1, 64);
    v += __shfl_xor(v, 2, 64);
    v += __shfl_xor(v, 4, 64);
    v += __shfl_xor(v, 8, 64);
    if (l16 == 0) l_sh[wid * 16 + quad * 4 + reg] = v;
  }
  __syncthreads();

  // ---- epilogue: O^T[d][q] / l(q) -> o_ws [B,S,H*256]
  const int b = bh >> 3, h = bh & 7;
#pragma unroll
  for (int nq = 0; nq < 4; nq++) {
    const int q = nq * 16 + l16;
    const float inv = 1.f / l_sh[q];
    const size_t base = ((size_t)b * SEQ + qt * 64 + q) * (NH * DM) + h * DM + wid * 64;
#pragma unroll
    for (int mi = 0; mi < 4; mi++) {
      short4 s4;
      s4.x = (short)f2bf(Oacc[mi][nq][0] * inv);
      s4.y = (short)f2bf(Oacc[mi][nq][1] * inv);
      s4.z = (short)f2bf(Oacc[mi][nq][2] * inv);
      s4.w = (short)f2bf(Oacc[mi][nq][3] * inv);
      *(short4*)(o_ws + base + mi * 16 + quad * 4) = s4;
    }
  }
}

// ---------------------------------------------------------------------------
// Kernel 3: output projection.  BM=32, BN=64, BK=128, grid (128,4).
// ---------------------------------------------------------------------------
__global__ __launch_bounds__(256) void outproj_kernel(
    const unsigned short* __restrict__ o_ws, const unsigned short* __restrict__ WoT,
    const float* __restrict__ bo, float* __restrict__ out) {
  __shared__ short a_lds[32][136];
  __shared__ short b_lds[64][136];

  const int tid = threadIdx.x;
  const int wid = tid >> 6, lane = tid & 63;
  const int quad = lane >> 4, l16 = lane & 15;
  const int wm = wid & 1, wn = wid >> 1;
  const int m0 = blockIdx.x * 32, n0 = blockIdx.y * 64;

  const f4 z4 = {0.f, 0.f, 0.f, 0.f};
  f4 acc[2];
#pragma unroll
  for (int i = 0; i < 2; i++) acc[i] = z4;

  const int ch = tid & 15, row = tid >> 4;
  for (int ko = 0; ko < 16; ko++) {
    const int k0 = ko * 128;
#pragma unroll
    for (int rb = 0; rb < 2; rb++) {
      int r = row + rb * 16;
      *(bf8*)(&a_lds[r][ch * 8]) = *(const bf8*)(o_ws + (size_t)(m0 + r) * 2048 + k0 + ch * 8);
    }
#pragma unroll
    for (int rb = 0; rb < 4; rb++) {
      int r = row + rb * 16;
      *(bf8*)(&b_lds[r][ch * 8]) = *(const bf8*)(WoT + (size_t)(n0 + r) * 2048 + k0 + ch * 8);
    }
    __syncthreads();
#pragma unroll
    for (int kc = 0; kc < 4; kc++) {
      const bf8 af = *(const bf8*)(&a_lds[wm * 16 + l16][kc * 32 + quad * 8]);
      bf8 bfv[2];
#pragma unroll
      for (int ni = 0; ni < 2; ni++)
        bfv[ni] = *(const bf8*)(&b_lds[wn * 32 + ni * 16 + l16][kc * 32 + quad * 8]);
#pragma unroll
      for (int ni = 0; ni < 2; ni++)
        acc[ni] = __builtin_amdgcn_mfma_f32_16x16x32_bf16(af, bfv[ni], acc[ni], 0, 0, 0);
    }
    __syncthreads();
  }
#pragma unroll
  for (int ni = 0; ni < 2; ni++) {
    const int n = n0 + wn * 32 + ni * 16 + l16;
    const float bv = bo[n];
#pragma unroll
    for (int reg = 0; reg < 4; reg++) {
      const int m = m0 + wm * 16 + quad * 4 + reg;
      out[(size_t)m * DM + n] = acc[ni][reg] + bv;
    }
  }
}

// ---------------------------------------------------------------------------
extern "C" void kernel_launch(void* const* d_in, const int* in_sizes, int n_in,
                              void* d_out, int out_size, void* d_ws, size_t ws_size,
                              hipStream_t stream) {
  const float* Q  = (const float*)d_in[0];
  const float* K  = (const float*)d_in[1];
  const float* V  = (const float*)d_in[2];
  const float* Wq = (const float*)d_in[3];
  const float* bq = (const float*)d_in[4];
  const float* Wk = (const float*)d_in[5];
  const float* bk = (const float*)d_in[6];
  const float* Wv = (const float*)d_in[7];
  const float* bv = (const float*)d_in[8];
  const float* Wo = (const float*)d_in[9];
  const float* bo = (const float*)d_in[10];
  float* out = (float*)d_out;

  char* ws = (char*)d_ws;
  const size_t QS = (size_t)NB * NH * SEQ * DM * 2;  // 16 MiB each
  unsigned short* q_frag = (unsigned short*)(ws);
  unsigned short* k_frag = (unsigned short*)(ws + QS);
  unsigned short* v_frag = (unsigned short*)(ws + 2 * QS);
  unsigned short* o_ws   = (unsigned short*)(ws + 3 * QS);
  const size_t WT = (size_t)2048 * 256 * 2;  // 1 MiB each
  unsigned short* Wt3 = (unsigned short*)(ws + 4 * QS);           // 3 MiB
  unsigned short* WoT = (unsigned short*)(ws + 4 * QS + 3 * WT);  // 1 MiB
  // Xbf (6 MiB) aliases o_ws: proj reads it before attn overwrites o_ws.
  unsigned short* Xbf = o_ws;

  prep_kernel<<<dim3(1024, 7), 256, 0, stream>>>(Wq, Wk, Wv, Wo, Q, K, V,
                                                 Wt3, WoT, Xbf);
  proj_kernel<<<dim3(32, 16, 3), 256, 0, stream>>>(Xbf, Wt3, bq, bk, bv,
                                                   q_frag, k_frag, v_frag);
  attn_kernel<<<512, 256, 0, stream>>>(q_frag, k_frag, v_frag, o_ws);
  outproj_kernel<<<dim3(128, 4), 256, 0, stream>>>(o_ws, WoT, bo, out);
}